// Round 6
// baseline (176.675 us; speedup 1.0000x reference)
//
#include <hip/hip_runtime.h>
#include <hip/hip_bf16.h>

// N=32 time, 32x32 grid, C=64 (H=4 x D=16), 3x3x3 offsets (M=27), 2 layers.
// R6: BCELLS=4 cells/block (weight L2 traffic /4: 900->225 MB), online-softmax
// fused K/V pass (each h-fragment ds_read once, per-cell state 10 VGPRs),
// transposed MFMA (A=W^T frag) as in R5. 3 launches.

typedef short short8_t __attribute__((ext_vector_type(8)));
typedef float floatx4 __attribute__((ext_vector_type(4)));

__device__ __forceinline__ short f2bs(float f) {
    __hip_bfloat16 h = __float2bfloat16(f);
    return *reinterpret_cast<short*>(&h);
}
// swizzled halo addressing: rowid in [0,324), 8 chunks of 8 shorts, pitch 64
__device__ __forceinline__ int hn_idx(int rowid, int chunk) {
    return rowid * 64 + ((chunk ^ (rowid & 7)) << 3);
}

// ---------------- prep: repack weights + BN partial sums ----------------
__global__ void prep_kernel(const float* __restrict__ Wq, const float* __restrict__ Wk,
                            const float* __restrict__ Wv, short* __restrict__ dst,
                            const float* __restrict__ x, float* __restrict__ sums) {
    if (blockIdx.x < 220) {
        int t = blockIdx.x * 256 + threadIdx.x;
        if (t >= 110 * 512) return;
        int mat  = t >> 9;
        int rem  = t & 511;
        int kk   = rem >> 8;
        int nt   = (rem >> 6) & 3;
        int lane = rem & 63;
        int krow = kk * 32 + (lane >> 4) * 8;
        int col  = nt * 16 + (lane & 15);
        const float* W;
        if (mat < 2)       W = Wq + mat * 4096;
        else if (mat < 56) W = Wk + (mat - 2) * 4096;
        else               W = Wv + (mat - 56) * 4096;
        short8_t v;
        #pragma unroll
        for (int j = 0; j < 8; ++j) v[j] = f2bs(W[(krow + j) * 64 + col]);
        *(short8_t*)&dst[(size_t)mat * 4096 + ((kk * 4 + nt) * 64 + lane) * 8] = v;
    } else {
        int bid = blockIdx.x - 220;
        int t = bid * 256 + threadIdx.x;
        const float4* x4 = (const float4*)x;
        float4 v0 = x4[t * 3 + 0], v1 = x4[t * 3 + 1], v2 = x4[t * 3 + 2];
        float vv[6];
        vv[0] = v0.x + v0.w + v1.z + v2.y;
        vv[1] = v0.y + v1.x + v1.w + v2.z;
        vv[2] = v0.z + v1.y + v2.x + v2.w;
        vv[3] = v0.x*v0.x + v0.w*v0.w + v1.z*v1.z + v2.y*v2.y;
        vv[4] = v0.y*v0.y + v1.x*v1.x + v1.w*v1.w + v2.z*v2.z;
        vv[5] = v0.z*v0.z + v1.y*v1.y + v2.x*v2.x + v2.w*v2.w;
        #pragma unroll
        for (int i = 0; i < 6; ++i) {
            #pragma unroll
            for (int off = 1; off < 64; off <<= 1) vv[i] += __shfl_xor(vv[i], off);
        }
        __shared__ float part[4][6];
        if ((threadIdx.x & 63) == 0) {
            #pragma unroll
            for (int i = 0; i < 6; ++i) part[threadIdx.x >> 6][i] = vv[i];
        }
        __syncthreads();
        if (threadIdx.x < 6)
            sums[bid * 8 + threadIdx.x] = part[0][threadIdx.x] + part[1][threadIdx.x] +
                                          part[2][threadIdx.x] + part[3][threadIdx.x];
    }
}

// ---------------- fused attention layer (4 cells/block, online softmax) --------
// grid (b=8, a=32, nb=2); block 256 = 4 waves; wave w = head w; cells bb0..bb0+3.
// Halo rows: rowid = (spa*6 + jcol)*18 + r, spa in [0,3), jcol in [0,6), r in [0,18).
template <bool FIRST>
__global__ __launch_bounds__(256, 2)
void layer_fused(const float* __restrict__ x, const float* __restrict__ sums,
                 const float* __restrict__ W_in, const float* __restrict__ b_in,
                 const float* __restrict__ hres, const short* __restrict__ hbf,
                 float* __restrict__ hout, short* __restrict__ hbfout,
                 const float* __restrict__ Wout, const float* __restrict__ bout,
                 float* __restrict__ out,
                 const short* __restrict__ wqB, const float* __restrict__ bq,
                 const short* __restrict__ wkB, const float* __restrict__ bk,
                 const short* __restrict__ wvB, const float* __restrict__ bv) {
    __shared__ short HnS[324 * 64];   // 41.5 KB, XOR-swizzled; reused as hf in LAST epilogue
    __shared__ float Waux[256];
    __shared__ float bn6[6];

    const int tid = threadIdx.x;
    const int bb0 = blockIdx.x * 4, a = blockIdx.y, nb = blockIdx.z;

    if (FIRST) {
        if (tid < 3) {
            float s = 0.f, qq = 0.f;
            #pragma unroll
            for (int p = 0; p < 32; ++p) { s += sums[p * 8 + tid]; qq += sums[p * 8 + 3 + tid]; }
            float mean = s * (1.f / 32768.f);
            float var  = qq * (1.f / 32768.f) - mean * mean;
            bn6[tid]     = mean;
            bn6[3 + tid] = rsqrtf(var + 1e-5f);
        }
        if (tid < 192) Waux[tid] = W_in[tid];
        else           Waux[tid] = b_in[tid - 192];
    } else {
        if (tid < 192)      Waux[tid] = Wout[tid];
        else if (tid < 195) Waux[tid] = bout[tid - 192];
    }
    __syncthreads();

    float mean0, mean1, mean2, rs0, rs1, rs2;
    if (FIRST) {
        mean0 = bn6[0]; mean1 = bn6[1]; mean2 = bn6[2];
        rs0 = bn6[3]; rs1 = bn6[4]; rs2 = bn6[5];
    }

    // ---- stage halo: 324 rows x 8 chunks of 8 bf16 ----
    for (int id = tid; id < 2592; id += 256) {
        int rowid = id >> 3, cc = id & 7;
        int r = rowid % 18;
        int rw = rowid / 18;           // spa*6 + jcol
        int spa = rw / 6, jcol = rw - spa * 6;
        int aa = a + spa - 1, bb = bb0 + jcol - 1;
        int n  = nb * 16 + r - 1;
        short8_t v = {0, 0, 0, 0, 0, 0, 0, 0};
        if ((unsigned)n < 32u && (unsigned)aa < 32u && (unsigned)bb < 32u) {
            int cell = (n * 32 + aa) * 32 + bb;
            if (FIRST) {
                float xn0 = (x[cell*3+0] - mean0) * rs0;
                float xn1 = (x[cell*3+1] - mean1) * rs1;
                float xn2 = (x[cell*3+2] - mean2) * rs2;
                #pragma unroll
                for (int j = 0; j < 8; ++j) {
                    int c = cc * 8 + j;
                    float h = Waux[192+c] + xn0*Waux[c] + xn1*Waux[64+c] + xn2*Waux[128+c];
                    v[j] = f2bs(h);
                }
            } else {
                v = *(const short8_t*)&hbf[cell * 64 + cc * 8];
            }
        }
        *(short8_t*)&HnS[hn_idx(rowid, cc)] = v;
    }
    __syncthreads();

    const int lane = tid & 63;
    const int w    = tid >> 6;       // head
    const int e    = lane & 15;      // column n (local time row)
    const int q    = lane >> 4;      // quad: local channel = q*4 + reg
    const int c0   = w * 16 + q * 4;

    // validity
    bool va[3], vb[6];
    #pragma unroll
    for (int d = 0; d < 3; ++d) va[d] = (unsigned)(a + d - 1) < 32u;
    #pragma unroll
    for (int j = 0; j < 6; ++j) vb[j] = (unsigned)(bb0 + j - 1) < 32u;

    // ---- Q^T projection per cell (center: spa=1, jcol=ci+1) ----
    floatx4 qv[4];
    {
        short8_t wq0 = *(const short8_t*)&wqB[((0 * 4 + w) * 64 + lane) * 8];
        short8_t wq1 = *(const short8_t*)&wqB[((1 * 4 + w) * 64 + lane) * 8];
        const float4 bq4 = *(const float4*)&bq[c0];
        #pragma unroll
        for (int ci = 0; ci < 4; ++ci) {
            const int row = (6 + ci + 1) * 18 + e + 1;
            short8_t h0 = *(const short8_t*)&HnS[hn_idx(row, q)];
            short8_t h1 = *(const short8_t*)&HnS[hn_idx(row, 4 + q)];
            floatx4 acc = {0, 0, 0, 0};
            acc = __builtin_amdgcn_mfma_f32_16x16x32_bf16(wq0, h0, acc, 0, 0, 0);
            acc = __builtin_amdgcn_mfma_f32_16x16x32_bf16(wq1, h1, acc, 0, 0, 0);
            qv[ci][0] = acc[0] + bq4.x; qv[ci][1] = acc[1] + bq4.y;
            qv[ci][2] = acc[2] + bq4.z; qv[ci][3] = acc[3] + bq4.w;
        }
    }

    // ---- fused K/V pass with online softmax ----
    floatx4 o[4] = {{0,0,0,0},{0,0,0,0},{0,0,0,0},{0,0,0,0}};
    float mx[4] = {-1e30f, -1e30f, -1e30f, -1e30f};
    float ss[4] = {0.f, 0.f, 0.f, 0.f};

    for (int sp = 0; sp < 9; ++sp) {
        const int di = sp / 3, dj = sp - di * 3;
        if (!va[di]) continue;
        const int rowb = (di * 6 + dj) * 18 + e;   // + ci*18 + t
        #pragma unroll
        for (int t = 0; t < 3; ++t) {
            const int m = t * 9 + sp;
            short8_t wk0 = *(const short8_t*)&wkB[m * 4096 + ((0 * 4 + w) * 64 + lane) * 8];
            short8_t wk1 = *(const short8_t*)&wkB[m * 4096 + ((1 * 4 + w) * 64 + lane) * 8];
            short8_t wv0 = *(const short8_t*)&wvB[m * 4096 + ((0 * 4 + w) * 64 + lane) * 8];
            short8_t wv1 = *(const short8_t*)&wvB[m * 4096 + ((1 * 4 + w) * 64 + lane) * 8];
            const float4 bk4 = *(const float4*)&bk[m * 64 + c0];
            const float4 bv4 = *(const float4*)&bv[m * 64 + c0];
            #pragma unroll
            for (int ci = 0; ci < 4; ++ci) {
                if (!vb[dj + ci]) continue;
                const int row = rowb + ci * 18 + t;
                short8_t h0 = *(const short8_t*)&HnS[hn_idx(row, q)];
                short8_t h1 = *(const short8_t*)&HnS[hn_idx(row, 4 + q)];
                floatx4 kacc = {0, 0, 0, 0};
                kacc = __builtin_amdgcn_mfma_f32_16x16x32_bf16(wk0, h0, kacc, 0, 0, 0);
                kacc = __builtin_amdgcn_mfma_f32_16x16x32_bf16(wk1, h1, kacc, 0, 0, 0);
                floatx4 vacc = {0, 0, 0, 0};
                vacc = __builtin_amdgcn_mfma_f32_16x16x32_bf16(wv0, h0, vacc, 0, 0, 0);
                vacc = __builtin_amdgcn_mfma_f32_16x16x32_bf16(wv1, h1, vacc, 0, 0, 0);
                float p = (kacc[0] + bk4.x) * qv[ci][0] + (kacc[1] + bk4.y) * qv[ci][1]
                        + (kacc[2] + bk4.z) * qv[ci][2] + (kacc[3] + bk4.w) * qv[ci][3];
                p += __shfl_xor(p, 16);
                p += __shfl_xor(p, 32);
                // branchless online softmax update
                float mnew  = fmaxf(mx[ci], p);
                float scale = __expf(mx[ci] - mnew);
                float wgt   = __expf(p - mnew);
                ss[ci] = ss[ci] * scale + wgt;
                mx[ci] = mnew;
                o[ci][0] = o[ci][0] * scale + wgt * (vacc[0] + bv4.x);
                o[ci][1] = o[ci][1] * scale + wgt * (vacc[1] + bv4.y);
                o[ci][2] = o[ci][2] * scale + wgt * (vacc[2] + bv4.z);
                o[ci][3] = o[ci][3] * scale + wgt * (vacc[3] + bv4.w);
            }
        }
    }
    #pragma unroll
    for (int ci = 0; ci < 4; ++ci) {
        float inv = 1.0f / ss[ci];
        o[ci][0] *= inv; o[ci][1] *= inv; o[ci][2] *= inv; o[ci][3] *= inv;
    }

    // ---- epilogue: lane owns row n = nb*16+e, channels c0..c0+3, 4 cells ----
    const int n = nb * 16 + e;
    if (FIRST) {
        #pragma unroll
        for (int ci = 0; ci < 4; ++ci) {
            int cell = (n * 32 + a) * 32 + bb0 + ci;
            float xn0 = (x[cell*3+0] - mean0) * rs0;
            float xn1 = (x[cell*3+1] - mean1) * rs1;
            float xn2 = (x[cell*3+2] - mean2) * rs2;
            float4 hv; float* hvp = (float*)&hv;
            short4 hb; short* hbp = (short*)&hb;
            #pragma unroll
            for (int i = 0; i < 4; ++i) {
                int c = c0 + i;
                float res = Waux[192+c] + xn0*Waux[c] + xn1*Waux[64+c] + xn2*Waux[128+c];
                float v = o[ci][i] + res;
                hvp[i] = v;
                hbp[i] = f2bs(v);
            }
            *(float4*)&hout[cell * 64 + c0] = hv;
            *(short4*)&hbfout[cell * 64 + c0] = hb;
        }
    } else {
        float4 res[4];
        #pragma unroll
        for (int ci = 0; ci < 4; ++ci)
            res[ci] = *(const float4*)&hres[((n * 32 + a) * 32 + bb0 + ci) * 64 + c0];
        __syncthreads();                   // all HnS reads done; overlay h_final
        float* hf = (float*)HnS;           // [4 cells][16 rows][pitch 68]
        #pragma unroll
        for (int ci = 0; ci < 4; ++ci) {
            float* d = &hf[(ci * 16 + e) * 68 + c0];
            d[0] = o[ci][0] + res[ci].x;
            d[1] = o[ci][1] + res[ci].y;
            d[2] = o[ci][2] + res[ci].z;
            d[3] = o[ci][3] + res[ci].w;
        }
        __syncthreads();
        if (tid < 192) {
            int rowglob = tid / 3, f = tid - rowglob * 3;   // rowglob = ci*16 + row
            int ci = rowglob >> 4, row = rowglob & 15;
            float acc = Waux[192 + f];
            #pragma unroll 8
            for (int cc = 0; cc < 64; ++cc) acc += hf[rowglob * 68 + cc] * Waux[cc * 3 + f];
            int nn = nb * 16 + row;
            out[((nn * 32 + a) * 32 + bb0 + ci) * 3 + f] = acc;
        }
    }
}

extern "C" void kernel_launch(void* const* d_in, const int* in_sizes, int n_in,
                              void* d_out, int out_size, void* d_ws, size_t ws_size,
                              hipStream_t stream) {
    const float* x     = (const float*)d_in[0];
    const float* W_in  = (const float*)d_in[1];
    const float* b_in  = (const float*)d_in[2];
    const float* W_out = (const float*)d_in[3];
    const float* b_out = (const float*)d_in[4];
    const float* Wq    = (const float*)d_in[5];
    const float* bq    = (const float*)d_in[6];
    const float* Wk    = (const float*)d_in[7];
    const float* bk    = (const float*)d_in[8];
    const float* Wv    = (const float*)d_in[9];
    const float* bv    = (const float*)d_in[10];

    float* ws    = (float*)d_ws;
    float* sums  = ws;                          // 32 x 8 floats (BN partials)
    float* h1    = ws + 256;                    // 2M floats (8 MB)
    short* h1bf  = (short*)(h1 + 2097152);      // 2M shorts (4 MB)
    short* wB    = h1bf + 2097152;              // 110 x 4096 bf16 (0.9 MB)

    prep_kernel<<<252, 256, 0, stream>>>(Wq, Wk, Wv, wB, x, sums);

    const short* wq0 = wB;                const short* wq1 = wB + 4096;
    const short* wk0 = wB + 2 * 4096;     const short* wk1 = wB + (2 + 27) * 4096;
    const short* wv0 = wB + 56 * 4096;    const short* wv1 = wB + (56 + 27) * 4096;

    dim3 grid(8, 32, 2);
    layer_fused<true><<<grid, 256, 0, stream>>>(
        x, sums, W_in, b_in, nullptr, nullptr, h1, h1bf,
        nullptr, nullptr, nullptr,
        wq0, bq, wk0, bk, wv0, bv);
    layer_fused<false><<<grid, 256, 0, stream>>>(
        nullptr, nullptr, nullptr, nullptr, h1, h1bf, nullptr, nullptr,
        W_out, b_out, (float*)d_out,
        wq1, bq + 64, wk1, bk + 1728, wv1, bv + 1728);
}

// Round 7
// 160.887 us; speedup vs baseline: 1.0981x; 1.0981x over previous
//
#include <hip/hip_runtime.h>
#include <hip/hip_bf16.h>

// N=32 time, 32x32 grid, C=64 (H=4 x D=16), 3x3x3 offsets (M=27), 2 layers.
// R7: 512-thread blocks; waves 0-3 (heads) do m in [0,14), waves 4-7 do [14,27);
// partial online-softmax states merged via flash-combine through the (dead) halo
// LDS. m-loop is runtime-bounded => small code (L1I-resident), 2x waves/CU,
// halved per-wave serial m-chain. BCELLS=4, transposed MFMA as R6.

typedef short short8_t __attribute__((ext_vector_type(8)));
typedef float floatx4 __attribute__((ext_vector_type(4)));

__device__ __forceinline__ short f2bs(float f) {
    __hip_bfloat16 h = __float2bfloat16(f);
    return *reinterpret_cast<short*>(&h);
}
// swizzled halo addressing: rowid in [0,324), 8 chunks of 8 shorts, pitch 64
__device__ __forceinline__ int hn_idx(int rowid, int chunk) {
    return rowid * 64 + ((chunk ^ (rowid & 7)) << 3);
}

// ---------------- prep: repack weights + BN partial sums ----------------
__global__ void prep_kernel(const float* __restrict__ Wq, const float* __restrict__ Wk,
                            const float* __restrict__ Wv, short* __restrict__ dst,
                            const float* __restrict__ x, float* __restrict__ sums) {
    if (blockIdx.x < 220) {
        int t = blockIdx.x * 256 + threadIdx.x;
        if (t >= 110 * 512) return;
        int mat  = t >> 9;
        int rem  = t & 511;
        int kk   = rem >> 8;
        int nt   = (rem >> 6) & 3;
        int lane = rem & 63;
        int krow = kk * 32 + (lane >> 4) * 8;
        int col  = nt * 16 + (lane & 15);
        const float* W;
        if (mat < 2)       W = Wq + mat * 4096;
        else if (mat < 56) W = Wk + (mat - 2) * 4096;
        else               W = Wv + (mat - 56) * 4096;
        short8_t v;
        #pragma unroll
        for (int j = 0; j < 8; ++j) v[j] = f2bs(W[(krow + j) * 64 + col]);
        *(short8_t*)&dst[(size_t)mat * 4096 + ((kk * 4 + nt) * 64 + lane) * 8] = v;
    } else {
        int bid = blockIdx.x - 220;
        int t = bid * 256 + threadIdx.x;
        const float4* x4 = (const float4*)x;
        float4 v0 = x4[t * 3 + 0], v1 = x4[t * 3 + 1], v2 = x4[t * 3 + 2];
        float vv[6];
        vv[0] = v0.x + v0.w + v1.z + v2.y;
        vv[1] = v0.y + v1.x + v1.w + v2.z;
        vv[2] = v0.z + v1.y + v2.x + v2.w;
        vv[3] = v0.x*v0.x + v0.w*v0.w + v1.z*v1.z + v2.y*v2.y;
        vv[4] = v0.y*v0.y + v1.x*v1.x + v1.w*v1.w + v2.z*v2.z;
        vv[5] = v0.z*v0.z + v1.y*v1.y + v2.x*v2.x + v2.w*v2.w;
        #pragma unroll
        for (int i = 0; i < 6; ++i) {
            #pragma unroll
            for (int off = 1; off < 64; off <<= 1) vv[i] += __shfl_xor(vv[i], off);
        }
        __shared__ float part[4][6];
        if ((threadIdx.x & 63) == 0) {
            #pragma unroll
            for (int i = 0; i < 6; ++i) part[threadIdx.x >> 6][i] = vv[i];
        }
        __syncthreads();
        if (threadIdx.x < 6)
            sums[bid * 8 + threadIdx.x] = part[0][threadIdx.x] + part[1][threadIdx.x] +
                                          part[2][threadIdx.x] + part[3][threadIdx.x];
    }
}

// ---------------- fused attention layer (8 waves, m-split, online softmax) -----
// grid (b=8, a=32, nb=2); block 512 = 8 waves; wave = (g2*4 + head);
// g2=0 -> m in [0,14), g2=1 -> m in [14,27). Cells bb0..bb0+3.
template <bool FIRST>
__global__ __launch_bounds__(512, 4)
void layer_fused(const float* __restrict__ x, const float* __restrict__ sums,
                 const float* __restrict__ W_in, const float* __restrict__ b_in,
                 const float* __restrict__ hres, const short* __restrict__ hbf,
                 float* __restrict__ hout, short* __restrict__ hbfout,
                 const float* __restrict__ Wout, const float* __restrict__ bout,
                 float* __restrict__ out,
                 const short* __restrict__ wqB, const float* __restrict__ bq,
                 const short* __restrict__ wkB, const float* __restrict__ bk,
                 const short* __restrict__ wvB, const float* __restrict__ bv) {
    __shared__ short HnS[324 * 64];   // 41.5 KB halo; reused for state merge + hf
    __shared__ float Waux[256];
    __shared__ float bn6[6];

    const int tid = threadIdx.x;
    const int bb0 = blockIdx.x * 4, a = blockIdx.y, nb = blockIdx.z;

    if (FIRST) {
        if (tid < 3) {
            float s = 0.f, qq = 0.f;
            #pragma unroll
            for (int p = 0; p < 32; ++p) { s += sums[p * 8 + tid]; qq += sums[p * 8 + 3 + tid]; }
            float mean = s * (1.f / 32768.f);
            float var  = qq * (1.f / 32768.f) - mean * mean;
            bn6[tid]     = mean;
            bn6[3 + tid] = rsqrtf(var + 1e-5f);
        }
        if (tid < 192)      Waux[tid] = W_in[tid];
        else if (tid < 256) Waux[tid] = b_in[tid - 192];
    } else {
        if (tid < 192)      Waux[tid] = Wout[tid];
        else if (tid < 195) Waux[tid] = bout[tid - 192];
    }
    __syncthreads();

    float mean0, mean1, mean2, rs0, rs1, rs2;
    if (FIRST) {
        mean0 = bn6[0]; mean1 = bn6[1]; mean2 = bn6[2];
        rs0 = bn6[3]; rs1 = bn6[4]; rs2 = bn6[5];
    }

    // ---- stage halo: 324 rows x 8 chunks of 8 bf16 ----
    for (int id = tid; id < 2592; id += 512) {
        int rowid = id >> 3, cc = id & 7;
        int r = rowid % 18;
        int rw = rowid / 18;           // spa*6 + jcol
        int spa = rw / 6, jcol = rw - spa * 6;
        int aa = a + spa - 1, bb = bb0 + jcol - 1;
        int n  = nb * 16 + r - 1;
        short8_t v = {0, 0, 0, 0, 0, 0, 0, 0};
        if ((unsigned)n < 32u && (unsigned)aa < 32u && (unsigned)bb < 32u) {
            int cell = (n * 32 + aa) * 32 + bb;
            if (FIRST) {
                float xn0 = (x[cell*3+0] - mean0) * rs0;
                float xn1 = (x[cell*3+1] - mean1) * rs1;
                float xn2 = (x[cell*3+2] - mean2) * rs2;
                #pragma unroll
                for (int j = 0; j < 8; ++j) {
                    int c = cc * 8 + j;
                    float h = Waux[192+c] + xn0*Waux[c] + xn1*Waux[64+c] + xn2*Waux[128+c];
                    v[j] = f2bs(h);
                }
            } else {
                v = *(const short8_t*)&hbf[cell * 64 + cc * 8];
            }
        }
        *(short8_t*)&HnS[hn_idx(rowid, cc)] = v;
    }
    __syncthreads();

    const int lane = tid & 63;
    const int wv8  = tid >> 6;       // 0..7
    const int w    = wv8 & 3;        // head
    const int g2   = wv8 >> 2;       // m-group
    const int e    = lane & 15;      // column n (local time row)
    const int q    = lane >> 4;      // quad: local channel = q*4 + reg
    const int c0   = w * 16 + q * 4;

    bool va[3], vb[6];
    #pragma unroll
    for (int d = 0; d < 3; ++d) va[d] = (unsigned)(a + d - 1) < 32u;
    #pragma unroll
    for (int j = 0; j < 6; ++j) vb[j] = (unsigned)(bb0 + j - 1) < 32u;

    // ---- Q^T projection per cell (center: spa=1, jcol=ci+1); both groups ----
    floatx4 qv[4];
    {
        short8_t wq0 = *(const short8_t*)&wqB[((0 * 4 + w) * 64 + lane) * 8];
        short8_t wq1 = *(const short8_t*)&wqB[((1 * 4 + w) * 64 + lane) * 8];
        const float4 bq4 = *(const float4*)&bq[c0];
        #pragma unroll
        for (int ci = 0; ci < 4; ++ci) {
            const int row = (6 + ci + 1) * 18 + e + 1;
            short8_t h0 = *(const short8_t*)&HnS[hn_idx(row, q)];
            short8_t h1 = *(const short8_t*)&HnS[hn_idx(row, 4 + q)];
            floatx4 acc = {0, 0, 0, 0};
            acc = __builtin_amdgcn_mfma_f32_16x16x32_bf16(wq0, h0, acc, 0, 0, 0);
            acc = __builtin_amdgcn_mfma_f32_16x16x32_bf16(wq1, h1, acc, 0, 0, 0);
            qv[ci][0] = acc[0] + bq4.x; qv[ci][1] = acc[1] + bq4.y;
            qv[ci][2] = acc[2] + bq4.z; qv[ci][3] = acc[3] + bq4.w;
        }
    }

    // ---- fused K/V pass with online softmax over this group's m-range ----
    floatx4 o[4] = {{0,0,0,0},{0,0,0,0},{0,0,0,0},{0,0,0,0}};
    float mx[4] = {-1e30f, -1e30f, -1e30f, -1e30f};
    float ss[4] = {0.f, 0.f, 0.f, 0.f};

    const int mstart = g2 ? 14 : 0;
    const int mend   = g2 ? 27 : 14;
    for (int m = mstart; m < mend; ++m) {          // rolled: small code, uniform branch
        const int t  = m / 9;
        const int sp = m - t * 9;
        const int di = sp / 3, dj = sp - di * 3;
        if (!va[di]) continue;
        short8_t wk0 = *(const short8_t*)&wkB[m * 4096 + ((0 * 4 + w) * 64 + lane) * 8];
        short8_t wk1 = *(const short8_t*)&wkB[m * 4096 + ((1 * 4 + w) * 64 + lane) * 8];
        short8_t wv0 = *(const short8_t*)&wvB[m * 4096 + ((0 * 4 + w) * 64 + lane) * 8];
        short8_t wv1 = *(const short8_t*)&wvB[m * 4096 + ((1 * 4 + w) * 64 + lane) * 8];
        const float4 bk4 = *(const float4*)&bk[m * 64 + c0];
        const float4 bv4 = *(const float4*)&bv[m * 64 + c0];
        const int rowb = (di * 6 + dj) * 18 + e + t;   // + ci*18
        #pragma unroll
        for (int ci = 0; ci < 4; ++ci) {
            if (!vb[dj + ci]) continue;
            const int row = rowb + ci * 18;
            short8_t h0 = *(const short8_t*)&HnS[hn_idx(row, q)];
            short8_t h1 = *(const short8_t*)&HnS[hn_idx(row, 4 + q)];
            floatx4 kacc = {0, 0, 0, 0};
            kacc = __builtin_amdgcn_mfma_f32_16x16x32_bf16(wk0, h0, kacc, 0, 0, 0);
            kacc = __builtin_amdgcn_mfma_f32_16x16x32_bf16(wk1, h1, kacc, 0, 0, 0);
            floatx4 vacc = {0, 0, 0, 0};
            vacc = __builtin_amdgcn_mfma_f32_16x16x32_bf16(wv0, h0, vacc, 0, 0, 0);
            vacc = __builtin_amdgcn_mfma_f32_16x16x32_bf16(wv1, h1, vacc, 0, 0, 0);
            float p = (kacc[0] + bk4.x) * qv[ci][0] + (kacc[1] + bk4.y) * qv[ci][1]
                    + (kacc[2] + bk4.z) * qv[ci][2] + (kacc[3] + bk4.w) * qv[ci][3];
            p += __shfl_xor(p, 16);
            p += __shfl_xor(p, 32);
            float mnew  = fmaxf(mx[ci], p);
            float scale = __expf(mx[ci] - mnew);
            float wgt   = __expf(p - mnew);
            ss[ci] = ss[ci] * scale + wgt;
            mx[ci] = mnew;
            o[ci][0] = o[ci][0] * scale + wgt * (vacc[0] + bv4.x);
            o[ci][1] = o[ci][1] * scale + wgt * (vacc[1] + bv4.y);
            o[ci][2] = o[ci][2] * scale + wgt * (vacc[2] + bv4.z);
            o[ci][3] = o[ci][3] * scale + wgt * (vacc[3] + bv4.w);
        }
    }

    // ---- flash-combine the two m-groups through (dead) halo LDS ----
    __syncthreads();                       // all HnS halo reads done
    float* stbuf = (float*)HnS;            // [head][lane][ci][6] = 6144 floats
    if (g2 == 1) {
        #pragma unroll
        for (int ci = 0; ci < 4; ++ci) {
            float* d = &stbuf[(((w * 64 + lane) * 4) + ci) * 6];
            d[0] = mx[ci]; d[1] = ss[ci];
            d[2] = o[ci][0]; d[3] = o[ci][1]; d[4] = o[ci][2]; d[5] = o[ci][3];
        }
    }
    __syncthreads();
    if (g2 == 0) {
        #pragma unroll
        for (int ci = 0; ci < 4; ++ci) {
            const float* d = &stbuf[(((w * 64 + lane) * 4) + ci) * 6];
            float m1 = d[0], s1 = d[1];
            float M  = fmaxf(mx[ci], m1);
            float e0 = __expf(mx[ci] - M);
            float e1 = __expf(m1 - M);
            float inv = 1.0f / (ss[ci] * e0 + s1 * e1);
            o[ci][0] = (o[ci][0] * e0 + d[2] * e1) * inv;
            o[ci][1] = (o[ci][1] * e0 + d[3] * e1) * inv;
            o[ci][2] = (o[ci][2] * e0 + d[4] * e1) * inv;
            o[ci][3] = (o[ci][3] * e0 + d[5] * e1) * inv;
        }
    }

    // ---- epilogue (g2==0 waves own the outputs) ----
    const int n = nb * 16 + e;
    if (FIRST) {
        if (g2 == 0) {
            #pragma unroll
            for (int ci = 0; ci < 4; ++ci) {
                int cell = (n * 32 + a) * 32 + bb0 + ci;
                float xn0 = (x[cell*3+0] - mean0) * rs0;
                float xn1 = (x[cell*3+1] - mean1) * rs1;
                float xn2 = (x[cell*3+2] - mean2) * rs2;
                float4 hv; float* hvp = (float*)&hv;
                short4 hb; short* hbp = (short*)&hb;
                #pragma unroll
                for (int i = 0; i < 4; ++i) {
                    int c = c0 + i;
                    float res = Waux[192+c] + xn0*Waux[c] + xn1*Waux[64+c] + xn2*Waux[128+c];
                    float v = o[ci][i] + res;
                    hvp[i] = v;
                    hbp[i] = f2bs(v);
                }
                *(float4*)&hout[cell * 64 + c0] = hv;
                *(short4*)&hbfout[cell * 64 + c0] = hb;
            }
        }
    } else {
        __syncthreads();                   // state reads done; reuse LDS for hf
        float* hf = (float*)HnS;           // [4 cells][16 rows][pitch 68]
        if (g2 == 0) {
            #pragma unroll
            for (int ci = 0; ci < 4; ++ci) {
                float4 res = *(const float4*)&hres[((n * 32 + a) * 32 + bb0 + ci) * 64 + c0];
                float* d = &hf[(ci * 16 + e) * 68 + c0];
                d[0] = o[ci][0] + res.x;
                d[1] = o[ci][1] + res.y;
                d[2] = o[ci][2] + res.z;
                d[3] = o[ci][3] + res.w;
            }
        }
        __syncthreads();
        if (tid < 192) {
            int rowglob = tid / 3, f = tid - rowglob * 3;   // rowglob = ci*16 + row
            int ci = rowglob >> 4, row = rowglob & 15;
            float acc = Waux[192 + f];
            #pragma unroll 8
            for (int cc = 0; cc < 64; ++cc) acc += hf[rowglob * 68 + cc] * Waux[cc * 3 + f];
            int nn = nb * 16 + row;
            out[((nn * 32 + a) * 32 + bb0 + ci) * 3 + f] = acc;
        }
    }
}

extern "C" void kernel_launch(void* const* d_in, const int* in_sizes, int n_in,
                              void* d_out, int out_size, void* d_ws, size_t ws_size,
                              hipStream_t stream) {
    const float* x     = (const float*)d_in[0];
    const float* W_in  = (const float*)d_in[1];
    const float* b_in  = (const float*)d_in[2];
    const float* W_out = (const float*)d_in[3];
    const float* b_out = (const float*)d_in[4];
    const float* Wq    = (const float*)d_in[5];
    const float* bq    = (const float*)d_in[6];
    const float* Wk    = (const float*)d_in[7];
    const float* bk    = (const float*)d_in[8];
    const float* Wv    = (const float*)d_in[9];
    const float* bv    = (const float*)d_in[10];

    float* ws    = (float*)d_ws;
    float* sums  = ws;                          // 32 x 8 floats (BN partials)
    float* h1    = ws + 256;                    // 2M floats (8 MB)
    short* h1bf  = (short*)(h1 + 2097152);      // 2M shorts (4 MB)
    short* wB    = h1bf + 2097152;              // 110 x 4096 bf16 (0.9 MB)

    prep_kernel<<<252, 256, 0, stream>>>(Wq, Wk, Wv, wB, x, sums);

    const short* wq0 = wB;                const short* wq1 = wB + 4096;
    const short* wk0 = wB + 2 * 4096;     const short* wk1 = wB + (2 + 27) * 4096;
    const short* wv0 = wB + 56 * 4096;    const short* wv1 = wB + (56 + 27) * 4096;

    dim3 grid(8, 32, 2);
    layer_fused<true><<<grid, 512, 0, stream>>>(
        x, sums, W_in, b_in, nullptr, nullptr, h1, h1bf,
        nullptr, nullptr, nullptr,
        wq0, bq, wk0, bk, wv0, bv);
    layer_fused<false><<<grid, 512, 0, stream>>>(
        nullptr, nullptr, nullptr, nullptr, h1, h1bf, nullptr, nullptr,
        W_out, b_out, (float*)d_out,
        wq1, bq + 64, wk1, bk + 1728, wv1, bv + 1728);
}